// Round 14
// baseline (53.924 us; speedup 1.0000x reference)
//
#include <hip/hip_runtime.h>
#include <stdint.h>

#define BATCH 128
#define MAXN 1024
#define NF 9
#define DIM 256
#define NCLS 10

// Combined-table sections (rows of 256):
#define BASE1 119
#define BASE2 179
#define BASE3 299
#define QROWS 443
#define TBLK 114   // 3 cls blocks + 111 Q blocks

typedef __attribute__((ext_vector_type(4))) float f32x4;
typedef __attribute__((ext_vector_type(2))) uint32_t u32x2;

__device__ __forceinline__ ushort f32_to_bf16_rne(float x) {
  uint32_t u = __float_as_uint(x);
  u += 0x7fffu + ((u >> 16) & 1u);
  return (ushort)(u >> 16);
}

__device__ __forceinline__ f32x4 bf4_to_f32x4(u32x2 v) {
  f32x4 r;
  r.x = __uint_as_float(v.x << 16);
  r.y = __uint_as_float(v.x & 0xffff0000u);
  r.z = __uint_as_float(v.y << 16);
  r.w = __uint_as_float(v.y & 0xffff0000u);
  return r;
}

// ---------------------------------------------------------------------------
// Prep (proven ~2.5us): 114 blocks, 4 table rows/block, one W sweep amortized.
//  bid in [0,3):   clsT[c][o] f32 = lin_b[o] + W2[o]·rxn_emb[c]
//  bid in [3,114): Qb[q][o] bf16 = W1[o]·S_q  (row-major 443x256)
// ---------------------------------------------------------------------------
__global__ __launch_bounds__(256) void prep_kernel(
    const float* __restrict__ rxn_emb, const float* __restrict__ lin_w,
    const float* __restrict__ lin_b, const float* __restrict__ atom_emb,
    ushort* __restrict__ Qb, float* __restrict__ clsT)
{
  __shared__ float S[4][DIM];
  const int bid = blockIdx.x;
  const int t = threadIdx.x;
  const bool isCls = bid < 3;
  const int row0 = isCls ? bid * 4 : (bid - 3) * 4;
  const int rmax = isCls ? NCLS : QROWS;
  const int nrows = (rmax - row0 < 4) ? (rmax - row0) : 4;

#pragma unroll
  for (int r = 0; r < 4; ++r) {
    float v = 0.f;
    if (r < nrows) {
      const int q = row0 + r;
      if (isCls) {
        v = rxn_emb[q * DIM + t];
      } else if (q < BASE1) {
        v = atom_emb[q * DIM + t];
      } else if (q < BASE2) {
        int x = q - BASE1;
        v = atom_emb[(119 + x / 12) * DIM + t] + atom_emb[(124 + x % 12) * DIM + t];
      } else if (q < BASE3) {
        int x = q - BASE2;
        v = atom_emb[(136 + x / 10) * DIM + t] + atom_emb[(148 + x % 10) * DIM + t];
      } else {
        int x = q - BASE3;
        int i8 = x & 1, i7 = (x >> 1) & 1, y = x >> 2;
        v = atom_emb[(158 + y / 6) * DIM + t] + atom_emb[(164 + y % 6) * DIM + t]
          + atom_emb[(170 + i7) * DIM + t] + atom_emb[(172 + i8) * DIM + t];
      }
    }
    S[r][t] = v;
  }
  __syncthreads();

  const float* wrow = lin_w + (size_t)t * 2 * DIM + (isCls ? DIM : 0);
  const float init = isCls ? lin_b[t] : 0.f;
  float a0 = init, a1 = init, a2 = init, a3 = init;
#pragma unroll 4
  for (int d = 0; d < DIM; d += 4) {
    float4 w4 = *(const float4*)(wrow + d);
    a0 += w4.x * S[0][d] + w4.y * S[0][d + 1] + w4.z * S[0][d + 2] + w4.w * S[0][d + 3];
    a1 += w4.x * S[1][d] + w4.y * S[1][d + 1] + w4.z * S[1][d + 2] + w4.w * S[1][d + 3];
    a2 += w4.x * S[2][d] + w4.y * S[2][d + 1] + w4.z * S[2][d + 2] + w4.w * S[2][d + 3];
    a3 += w4.x * S[3][d] + w4.y * S[3][d + 1] + w4.z * S[3][d + 2] + w4.w * S[3][d + 3];
  }
  if (isCls) {
    if (0 < nrows) clsT[(row0 + 0) * DIM + t] = a0;
    if (1 < nrows) clsT[(row0 + 1) * DIM + t] = a1;
    if (2 < nrows) clsT[(row0 + 2) * DIM + t] = a2;
    if (3 < nrows) clsT[(row0 + 3) * DIM + t] = a3;
  } else {
    if (0 < nrows) Qb[(row0 + 0) * DIM + t] = f32_to_bf16_rne(a0);
    if (1 < nrows) Qb[(row0 + 1) * DIM + t] = f32_to_bf16_rne(a1);
    if (2 < nrows) Qb[(row0 + 2) * DIM + t] = f32_to_bf16_rne(a2);
    if (3 < nrows) Qb[(row0 + 3) * DIM + t] = f32_to_bf16_rne(a3);
  }
}

// ---------------------------------------------------------------------------
// Fill kernel — PURE STORE STREAM (structurally = rocclr fillBuffer, which
// hits 6.7 TB/s at 10% occupancy). Per batch, masked rows [nn,1024) are one
// CONTIGUOUS span. 8 blocks/batch grid-stride it; stride (2048 f32x4) ≡ 0
// mod 64, so each thread's output column is loop-invariant -> cf loaded ONCE,
// then nothing but back-to-back coalesced stores. Zero loads in the loop.
// ---------------------------------------------------------------------------
__global__ __launch_bounds__(256) void fill_kernel(
    const int* __restrict__ num_nodes, const int* __restrict__ rxn_class,
    const float* __restrict__ clsT, float* __restrict__ out)
{
  const int b = blockIdx.x >> 3;
  const int k = blockIdx.x & 7;
  const int t = threadIdx.x;
  const int nn = num_nodes[b];
  const f32x4 cf = ((const f32x4*)clsT)[rxn_class[b] * 64 + (t & 63)];
  f32x4* __restrict__ out4 = (f32x4*)out;
  const size_t end = ((size_t)b * MAXN + MAXN) * 64;
  for (size_t i = ((size_t)b * MAXN + nn) * 64 + k * 256 + t; i < end; i += 2048)
    out4[i] = cf;
}

// ---------------------------------------------------------------------------
// Gather kernel — valid rows ONLY (masked waves return without storing).
// r8's proven body: wave = 8 rows; per row 9 idx loads + 4 bf16 gathers +
// 1 f32x4 store. No mask arithmetic, no fill stores mixed into the stream.
// ---------------------------------------------------------------------------
__global__ __launch_bounds__(256) void gather_kernel(
    const int* __restrict__ node_feat, const int* __restrict__ num_nodes,
    const int* __restrict__ rxn_class,
    const ushort* __restrict__ Qb, const float* __restrict__ clsT,
    float* __restrict__ out)
{
  const int tid = threadIdx.x;
  const int lane = tid & 63;
  const int w = __builtin_amdgcn_readfirstlane(tid >> 6);
  const int wid = blockIdx.x * 4 + w;   // 0..16383
  const int b = wid >> 7;               // 128 waves per batch
  const int n0 = (wid & 127) << 3;      // 8 rows per wave
  const int nn = num_nodes[b];

  if (n0 >= nn) return;  // fully masked: handled by fill_kernel

  const f32x4 cf = ((const f32x4*)clsT)[rxn_class[b] * 64 + lane];
  f32x4* __restrict__ outp = (f32x4*)out + ((size_t)(b * MAXN + n0)) * 64 + lane;
  const int* __restrict__ p = node_feat + (size_t)(b * MAXN + n0) * NF;
  const u32x2* __restrict__ Q2 = (const u32x2*)Qb;

  if (n0 + 8 <= nn) {  // full wave — straight-line
#pragma unroll 4
    for (int i = 0; i < 8; ++i) {
      const int j0 = p[i * NF + 0];
      const int j1 = BASE1 + p[i * NF + 1] * 12 + p[i * NF + 2];
      const int j2 = BASE2 + p[i * NF + 3] * 10 + p[i * NF + 4];
      const int j3 = BASE3 + ((p[i * NF + 5] * 6 + p[i * NF + 6]) * 2 + p[i * NF + 7]) * 2 + p[i * NF + 8];
      const u32x2 v0 = Q2[j0 * 64 + lane];
      const u32x2 v1 = Q2[j1 * 64 + lane];
      const u32x2 v2 = Q2[j2 * 64 + lane];
      const u32x2 v3 = Q2[j3 * 64 + lane];
      const f32x4 s = (bf4_to_f32x4(v0) + bf4_to_f32x4(v1))
                    + (bf4_to_f32x4(v2) + bf4_to_f32x4(v3));
      outp[i * 64] = cf + s;
    }
    return;
  }

  // boundary wave (<=1 per batch): store only rows < nn
  const int lim = nn - n0;
  for (int i = 0; i < lim; ++i) {
    const int j0 = p[i * NF + 0];
    const int j1 = BASE1 + p[i * NF + 1] * 12 + p[i * NF + 2];
    const int j2 = BASE2 + p[i * NF + 3] * 10 + p[i * NF + 4];
    const int j3 = BASE3 + ((p[i * NF + 5] * 6 + p[i * NF + 6]) * 2 + p[i * NF + 7]) * 2 + p[i * NF + 8];
    const u32x2 v0 = Q2[j0 * 64 + lane];
    const u32x2 v1 = Q2[j1 * 64 + lane];
    const u32x2 v2 = Q2[j2 * 64 + lane];
    const u32x2 v3 = Q2[j3 * 64 + lane];
    const f32x4 s = (bf4_to_f32x4(v0) + bf4_to_f32x4(v1))
                  + (bf4_to_f32x4(v2) + bf4_to_f32x4(v3));
    outp[i * 64] = cf + s;
  }
}

extern "C" void kernel_launch(void* const* d_in, const int* in_sizes, int n_in,
                              void* d_out, int out_size, void* d_ws, size_t ws_size,
                              hipStream_t stream) {
  const int* node_feat = (const int*)d_in[0];
  const int* num_nodes = (const int*)d_in[1];
  const int* rxn_class = (const int*)d_in[2];
  const float* atom_emb = (const float*)d_in[3];
  const float* rxn_emb = (const float*)d_in[4];
  const float* lin_w = (const float*)d_in[5];
  const float* lin_b = (const float*)d_in[6];
  float* outp = (float*)d_out;

  // workspace: Qb row-major bf16 (226816 B) | clsT (10240 B)
  ushort* Qb = (ushort*)d_ws;
  float* clsT = (float*)((char*)d_ws + QROWS * DIM * sizeof(ushort));

  prep_kernel<<<TBLK, 256, 0, stream>>>(rxn_emb, lin_w, lin_b, atom_emb,
                                        Qb, clsT);
  fill_kernel<<<BATCH * 8, 256, 0, stream>>>(num_nodes, rxn_class, clsT, outp);
  gather_kernel<<<4096, 256, 0, stream>>>(node_feat, num_nodes, rxn_class,
                                          Qb, clsT, outp);
}

// Round 15
// 40.854 us; speedup vs baseline: 1.3199x; 1.3199x over previous
//
#include <hip/hip_runtime.h>
#include <stdint.h>

#define BATCH 128
#define MAXN 1024
#define NF 9
#define DIM 256
#define NCLS 10

// Combined-table sections (rows of 256):
#define BASE1 119
#define BASE2 179
#define BASE3 299
#define QROWS 443
#define TBLK 114   // 3 cls blocks + 111 Q blocks

typedef __attribute__((ext_vector_type(4))) float f32x4;

__device__ __forceinline__ ushort f32_to_bf16_rne(float x) {
  uint32_t u = __float_as_uint(x);
  u += 0x7fffu + ((u >> 16) & 1u);
  return (ushort)(u >> 16);
}

// ---------------------------------------------------------------------------
// Prep (proven ~2.5us): 114 blocks, 4 table rows/block, one W sweep amortized.
//  bid in [0,3):   clsT[c][o] f32 = lin_b[o] + W2[o]·rxn_emb[c]
//  bid in [3,114): Qb[q][o] bf16 = W1[o]·S_q  (row-major 443x256, 512B rows)
// ---------------------------------------------------------------------------
__global__ __launch_bounds__(256) void prep_kernel(
    const float* __restrict__ rxn_emb, const float* __restrict__ lin_w,
    const float* __restrict__ lin_b, const float* __restrict__ atom_emb,
    ushort* __restrict__ Qb, float* __restrict__ clsT)
{
  __shared__ float S[4][DIM];
  const int bid = blockIdx.x;
  const int t = threadIdx.x;
  const bool isCls = bid < 3;
  const int row0 = isCls ? bid * 4 : (bid - 3) * 4;
  const int rmax = isCls ? NCLS : QROWS;
  const int nrows = (rmax - row0 < 4) ? (rmax - row0) : 4;

#pragma unroll
  for (int r = 0; r < 4; ++r) {
    float v = 0.f;
    if (r < nrows) {
      const int q = row0 + r;
      if (isCls) {
        v = rxn_emb[q * DIM + t];
      } else if (q < BASE1) {
        v = atom_emb[q * DIM + t];
      } else if (q < BASE2) {
        int x = q - BASE1;
        v = atom_emb[(119 + x / 12) * DIM + t] + atom_emb[(124 + x % 12) * DIM + t];
      } else if (q < BASE3) {
        int x = q - BASE2;
        v = atom_emb[(136 + x / 10) * DIM + t] + atom_emb[(148 + x % 10) * DIM + t];
      } else {
        int x = q - BASE3;
        int i8 = x & 1, i7 = (x >> 1) & 1, y = x >> 2;
        v = atom_emb[(158 + y / 6) * DIM + t] + atom_emb[(164 + y % 6) * DIM + t]
          + atom_emb[(170 + i7) * DIM + t] + atom_emb[(172 + i8) * DIM + t];
      }
    }
    S[r][t] = v;
  }
  __syncthreads();

  const float* wrow = lin_w + (size_t)t * 2 * DIM + (isCls ? DIM : 0);
  const float init = isCls ? lin_b[t] : 0.f;
  float a0 = init, a1 = init, a2 = init, a3 = init;
#pragma unroll 4
  for (int d = 0; d < DIM; d += 4) {
    float4 w4 = *(const float4*)(wrow + d);
    a0 += w4.x * S[0][d] + w4.y * S[0][d + 1] + w4.z * S[0][d + 2] + w4.w * S[0][d + 3];
    a1 += w4.x * S[1][d] + w4.y * S[1][d + 1] + w4.z * S[1][d + 2] + w4.w * S[1][d + 3];
    a2 += w4.x * S[2][d] + w4.y * S[2][d + 1] + w4.z * S[2][d + 2] + w4.w * S[2][d + 3];
    a3 += w4.x * S[3][d] + w4.y * S[3][d + 1] + w4.z * S[3][d + 2] + w4.w * S[3][d + 3];
  }
  if (isCls) {
    if (0 < nrows) clsT[(row0 + 0) * DIM + t] = a0;
    if (1 < nrows) clsT[(row0 + 1) * DIM + t] = a1;
    if (2 < nrows) clsT[(row0 + 2) * DIM + t] = a2;
    if (3 < nrows) clsT[(row0 + 3) * DIM + t] = a3;
  } else {
    if (0 < nrows) Qb[(row0 + 0) * DIM + t] = f32_to_bf16_rne(a0);
    if (1 < nrows) Qb[(row0 + 1) * DIM + t] = f32_to_bf16_rne(a1);
    if (2 < nrows) Qb[(row0 + 2) * DIM + t] = f32_to_bf16_rne(a2);
    if (3 < nrows) Qb[(row0 + 3) * DIM + t] = f32_to_bf16_rne(a3);
  }
}

// ---------------------------------------------------------------------------
// Main: r8 skeleton (4096 blocks x 256 thr, wave = 8 nodes, combined fill),
// SINGLE CHANGE: WIDE PAIRED GATHERS. Per node, 2x b128 gathers (16B/lane;
// lanes 0-31 carry the FULL row jA/jC, lanes 32-63 carry jB/jD — one instr
// reads two whole 512B rows) replace 4x b64 (8B/lane). Half-wave partials
// (A+C)/(B+D) are combined with 4 __shfl_xor(..,32). Per node: 3 VMEM
// (was 5), all max-width. Model from 12 rounds of falsifications: per-CU
// load-return rate is instruction/lane-width limited (~5 B/cyc at 8B/lane,
// ~10 B/cyc at 16B/lane streaming) — this doubles gather-side throughput.
// Store layout slot=2*li+hi keeps the 1KB/wave store fully coalesced.
// ---------------------------------------------------------------------------
__global__ __launch_bounds__(256) void main_kernel(
    const int* __restrict__ node_feat, const int* __restrict__ num_nodes,
    const int* __restrict__ rxn_class,
    const ushort* __restrict__ Qb, const float* __restrict__ clsT,
    float* __restrict__ out)
{
  const int tid = threadIdx.x;
  const int lane = tid & 63;
  const int w = __builtin_amdgcn_readfirstlane(tid >> 6);
  const int wid = blockIdx.x * 4 + w;   // 0..16383
  const int b = wid >> 7;               // 128 waves per batch
  const int n0 = (wid & 127) << 3;      // 8 nodes per wave
  const int nn = num_nodes[b];

  const int li = lane & 31;
  const int hi = lane >> 5;             // half-wave id
  const int slot = 2 * li + hi;         // f32x4 slot in the 256-col row

  const f32x4 cf = ((const f32x4*)clsT)[rxn_class[b] * 64 + slot];
  f32x4* __restrict__ outp = (f32x4*)out + ((size_t)(b * MAXN + n0)) * 64 + slot;

  if (n0 >= nn) {  // fully masked strip: pure b128 store stream
#pragma unroll
    for (int i = 0; i < 8; ++i)
      outp[i * 64] = cf;
    return;
  }

  const int* __restrict__ p = node_feat + (size_t)(b * MAXN + n0) * NF;

#define NODE_BODY(i, MASKED)                                                   \
  {                                                                            \
    const int j0 = p[(i) * NF + 0];                                            \
    const int j1 = BASE1 + p[(i) * NF + 1] * 12 + p[(i) * NF + 2];             \
    const int j2 = BASE2 + p[(i) * NF + 3] * 10 + p[(i) * NF + 4];             \
    const int j3 = BASE3 + ((p[(i) * NF + 5] * 6 + p[(i) * NF + 6]) * 2        \
                            + p[(i) * NF + 7]) * 2 + p[(i) * NF + 8];          \
    const int rAB = hi ? j1 : j0;                                              \
    const int rCD = hi ? j3 : j2;                                              \
    const uint4 g1 = *(const uint4*)(Qb + rAB * 256 + li * 8);                 \
    const uint4 g2 = *(const uint4*)(Qb + rCD * 256 + li * 8);                 \
    float pp[8];                                                               \
    pp[0] = __uint_as_float(g1.x << 16) + __uint_as_float(g2.x << 16);         \
    pp[1] = __uint_as_float(g1.x & 0xffff0000u) + __uint_as_float(g2.x & 0xffff0000u); \
    pp[2] = __uint_as_float(g1.y << 16) + __uint_as_float(g2.y << 16);         \
    pp[3] = __uint_as_float(g1.y & 0xffff0000u) + __uint_as_float(g2.y & 0xffff0000u); \
    pp[4] = __uint_as_float(g1.z << 16) + __uint_as_float(g2.z << 16);         \
    pp[5] = __uint_as_float(g1.z & 0xffff0000u) + __uint_as_float(g2.z & 0xffff0000u); \
    pp[6] = __uint_as_float(g1.w << 16) + __uint_as_float(g2.w << 16);         \
    pp[7] = __uint_as_float(g1.w & 0xffff0000u) + __uint_as_float(g2.w & 0xffff0000u); \
    f32x4 tot;                                                                 \
    _Pragma("unroll")                                                          \
    for (int k = 0; k < 4; ++k) {                                              \
      const float send = hi ? pp[k] : pp[4 + k];   /* what partner needs */    \
      const float own  = hi ? pp[4 + k] : pp[k];   /* my stored half */        \
      const float recv = __shfl_xor(send, 32, 64);                             \
      tot[k] = MASKED ? (cf[k] + mval * (own + recv)) : (cf[k] + own + recv);  \
    }                                                                          \
    outp[(i) * 64] = tot;                                                      \
  }

  if (n0 + 8 <= nn) {  // fully valid strip
    const float mval = 1.f; (void)mval;
#pragma unroll 4
    for (int i = 0; i < 8; ++i)
      NODE_BODY(i, 0)
    return;
  }

  // partial strip (<=1 per batch): branchless float-mask (gathers always
  // safe — all node_feat slots hold valid categorical indices)
#pragma unroll 4
  for (int i = 0; i < 8; ++i) {
    const float mval = (n0 + i < nn) ? 1.f : 0.f;
    NODE_BODY(i, 1)
  }
#undef NODE_BODY
}

extern "C" void kernel_launch(void* const* d_in, const int* in_sizes, int n_in,
                              void* d_out, int out_size, void* d_ws, size_t ws_size,
                              hipStream_t stream) {
  const int* node_feat = (const int*)d_in[0];
  const int* num_nodes = (const int*)d_in[1];
  const int* rxn_class = (const int*)d_in[2];
  const float* atom_emb = (const float*)d_in[3];
  const float* rxn_emb = (const float*)d_in[4];
  const float* lin_w = (const float*)d_in[5];
  const float* lin_b = (const float*)d_in[6];
  float* outp = (float*)d_out;

  // workspace: Qb row-major bf16 (226816 B) | clsT (10240 B)
  ushort* Qb = (ushort*)d_ws;
  float* clsT = (float*)((char*)d_ws + QROWS * DIM * sizeof(ushort));

  prep_kernel<<<TBLK, 256, 0, stream>>>(rxn_emb, lin_w, lin_b, atom_emb,
                                        Qb, clsT);
  main_kernel<<<4096, 256, 0, stream>>>(node_feat, num_nodes, rxn_class,
                                        Qb, clsT, outp);
}